// Round 7
// baseline (330.145 us; speedup 1.0000x reference)
//
#include <hip/hip_runtime.h>
#include <stdint.h>

#define NAC 147456   // 128*128*9
#define NGT 64
#define NB  8
#define APT 3        // 3 anchors/thread -> 1536 blocks = 6/CU, ALL co-resident
#define BLK 256
#define GX  (NAC / (BLK * APT))   // 192

// ---------------- Threefry-2x32 (JAX-compatible, 20 rounds) ----------------
__host__ __device__ static inline uint32_t tf_rotl(uint32_t x, uint32_t d) {
  return (x << d) | (x >> (32u - d));
}

__host__ __device__ static inline void threefry2x32(
    uint32_t k0, uint32_t k1, uint32_t x0, uint32_t x1,
    uint32_t* o0, uint32_t* o1)
{
  const uint32_t ks2 = k0 ^ k1 ^ 0x1BD11BDAu;
  x0 += k0; x1 += k1;
#define TFR(r) { x0 += x1; x1 = tf_rotl(x1, (r)); x1 ^= x0; }
  TFR(13u) TFR(15u) TFR(26u) TFR(6u)   x0 += k1;  x1 += ks2 + 1u;
  TFR(17u) TFR(29u) TFR(16u) TFR(24u)  x0 += ks2; x1 += k0 + 2u;
  TFR(13u) TFR(15u) TFR(26u) TFR(6u)   x0 += k0;  x1 += k1 + 3u;
  TFR(17u) TFR(29u) TFR(16u) TFR(24u)  x0 += k1;  x1 += ks2 + 4u;
  TFR(13u) TFR(15u) TFR(26u) TFR(6u)   x0 += ks2; x1 += k0 + 5u;
#undef TFR
  *o0 = x0; *o1 = x1;
}

__device__ static inline float4 bbox2delta_calc(const float4& a, const float4& g)
{
  const float wr  = a.w - a.y,          hr  = a.z - a.x;
  const float xcr = a.y + 0.5f * wr,    ycr = a.x + 0.5f * hr;
  const float wrc = fmaxf(wr, 1e-5f),   hrc = fmaxf(hr, 1e-5f);
  const float wl  = g.w - g.y,          hl  = g.z - g.x;
  const float xcl = g.y + 0.5f * wl,    ycl = g.x + 0.5f * hl;
  float4 r;
  r.x = fminf(fmaxf((xcl - xcr) / wrc, -10.0f), 10.0f);
  r.y = fminf(fmaxf((ycl - ycr) / hrc, -10.0f), 10.0f);
  r.z = fminf(fmaxf(__logf(wl / wrc),  -10.0f), 10.0f);
  r.w = fminf(fmaxf(__logf(hl / hrc),  -10.0f), 10.0f);
  return r;
}

// ---------------- Fused kernel, PLAIN launch, spin grid-barrier --------------
// Round-16. History: k1 inner loop pinned at 43-45us across 4 structures
// (dense/SMEM/pipelined/APT-1-full-occupancy) -> issue-bound, not worth more
// blind rounds. Budget: ~44us harness fill (fixed) + ~44.7 k1 + ~28 k2+gaps.
// Attack the 28: fuse k1+k2 WITHOUT hipLaunchCooperativeKernel (r13's failure
// was the cooperative LAUNCH PATH under graph capture; the fused GPU compute
// itself ran <=43us). Safety of spin-barrier WITHOUT cooperative guarantee:
//   grid = 1536 blocks = 6/CU exactly; capacity = 8/CU (LDS 2KB -> 80,
//   VGPR capped 85 via __launch_bounds__(256,6) -> >=6 blocks/CU; natural
//   use was 44-48 so the cap is slack, no spill risk). All blocks co-resident
//   => per-image arrive-then-spin barrier cannot deadlock.
// Phase 1 = proven r12 loop (T-form compare, quad-prefetch, bit-identical
// pos threshold via one IEEE div/anchor in reference rounding order).
// Leader: atomicAdd(cnt[b], s_cnt) relaxed; atomicAdd(arr[b],1) RELEASE;
// spin ACQUIRE until arr[b]==GX (s_sleep backoff); tot -> th.
// Phase 2: per anchor, exec-masked threefry (~2% lanes), one 16B store of
// delta or zeros to out[4..7] (write volume unchanged; flags buffer GONE).
__global__ __launch_bounds__(BLK, 6) void k_fused(
    const float* __restrict__ anchors,
    const float* __restrict__ gt,
    const float* __restrict__ deltas,
    float* __restrict__ out,
    int* __restrict__ cnt,              // [NB], zeroed by host memset
    int* __restrict__ arr,              // [NB], zeroed by host memset
    uint32_t kp0, uint32_t kp1)
{
  __shared__ __align__(16) float4 gbox[NGT];
  __shared__ __align__(16) float  garea[NGT];   // ga_j (exact, epilogue den)
  __shared__ __align__(16) float  gae[NGT];     // ga_j + EPS (T_j in compare)
  __shared__ int s_cnt;
  __shared__ int s_tot;
  const int b   = blockIdx.y;
  const int tid = threadIdx.x;

  if (tid == 0) s_cnt = 0;
  if (tid < NGT) {
    float4 g = reinterpret_cast<const float4*>(gt)[b * NGT + tid];
    const float ga = fmaxf(g.z - g.x, 0.0f) * fmaxf(g.w - g.y, 0.0f);
    gbox[tid]  = g;
    garea[tid] = ga;
    gae[tid]   = ga + 1e-5f;
  }
  __syncthreads();

  const int base = blockIdx.x * (BLK * APT) + tid;

  float4 a[APT];
  float  areaA[APT], num[APT], Tb[APT];
  int    bidx[APT];
#pragma unroll
  for (int t = 0; t < APT; ++t) {
    a[t] = reinterpret_cast<const float4*>(anchors)[base + t * BLK];
    areaA[t] = fmaxf(a[t].z - a[t].x, 0.0f) * fmaxf(a[t].w - a[t].y, 0.0f);
    num[t]  = 0.0f;   // incumbent inter
    Tb[t]   = 1.0f;   // incumbent S+e; any >0 gives "update iff inter>0" init
    bidx[t] = 0;
  }

#define IOU_ONE(gv, te, jv)                                              \
  {                                                                      \
    const float4 g_ = (gv);                                              \
    const float  te_ = (te);                                             \
    const int    j_  = (jv);                                             \
    _Pragma("unroll")                                                    \
    for (int t = 0; t < APT; ++t) {                                      \
      float yi = fmaxf(a[t].x, g_.x);                                    \
      float xi = fmaxf(a[t].y, g_.y);                                    \
      float ya = fminf(a[t].z, g_.z);                                    \
      float xa = fminf(a[t].w, g_.w);                                    \
      float inter = fmaxf(ya - yi, 0.0f) * (xa - xi);                    \
      float Tj = areaA[t] + te_;                                         \
      bool upd = inter * Tb[t] > num[t] * Tj;                            \
      num[t]  = upd ? inter : num[t];                                    \
      Tb[t]   = upd ? Tj    : Tb[t];                                     \
      bidx[t] = upd ? j_    : bidx[t];                                   \
    }                                                                    \
  }

  for (int jj = 0; jj < NGT; jj += 4) {
    const float4 te4 = *reinterpret_cast<const float4*>(&gae[jj]);
    const float4 g0 = gbox[jj + 0];
    const float4 g1 = gbox[jj + 1];
    const float4 g2 = gbox[jj + 2];
    const float4 g3 = gbox[jj + 3];
    IOU_ONE(g0, te4.x, jj + 0)
    IOU_ONE(g1, te4.y, jj + 1)
    IOU_ONE(g2, te4.z, jj + 2)
    IOU_ONE(g3, te4.w, jj + 3)
  }
#undef IOU_ONE

  // ---- phase-1 epilogue: proposals + pos mask in registers + count ----
  int posm = 0;
  int npos = 0;
#pragma unroll
  for (int t = 0; t < APT; ++t) {
    const int i = base + t * BLK;
    // Exact reference rounding order for the pos test:
    const float gaB = garea[bidx[t]];
    const float den = ((areaA[t] + gaB) - num[t]) + 1e-5f;
    const float best_iou = (10000.0f * num[t]) / den;
    const bool pos = best_iou > 5000.0f;
    posm |= (pos ? 1 : 0) << t;

    const float4 d = reinterpret_cast<const float4*>(deltas)[b * NAC + i];
    const float wb = a[t].w - a[t].y, hb = a[t].z - a[t].x;
    const float xc = a[t].y + 0.5f * wb + wb * d.x;
    const float yc = a[t].x + 0.5f * hb + hb * d.y;
    const float w_ = wb * __expf(d.z);
    const float h_ = hb * __expf(d.w);

    float* rowp = out + ((size_t)b * NAC + i) * 8;
    reinterpret_cast<float4*>(rowp)[0] =
        make_float4(yc - 0.5f * h_, xc - 0.5f * w_, yc + 0.5f * h_, xc + 0.5f * w_);

    unsigned long long m = __ballot(pos);
    if ((tid & 63) == 0) npos += (int)__popcll(m);
  }
  if ((tid & 63) == 0 && npos)
    atomicAdd(&s_cnt, npos);
  __syncthreads();

  // ---- arrive + spin grid-barrier (per image b; 192 blocks each) ----
  if (tid == 0) {
    if (s_cnt)
      __hip_atomic_fetch_add(&cnt[b], s_cnt, __ATOMIC_RELAXED,
                             __HIP_MEMORY_SCOPE_AGENT);
    __hip_atomic_fetch_add(&arr[b], 1, __ATOMIC_RELEASE,
                           __HIP_MEMORY_SCOPE_AGENT);
    while (__hip_atomic_load(&arr[b], __ATOMIC_ACQUIRE,
                             __HIP_MEMORY_SCOPE_AGENT) < GX) {
      __builtin_amdgcn_s_sleep(2);
    }
    s_tot = __hip_atomic_load(&cnt[b], __ATOMIC_RELAXED,
                              __HIP_MEMORY_SCOPE_AGENT);
  }
  __syncthreads();

  // ---- phase 2: sparse sampling, one 16B store per anchor ----
  const float th = 128.0f / ((float)s_tot + 1e-6f);

#pragma unroll
  for (int t = 0; t < APT; ++t) {
    const int i = base + t * BLK;
    const int f = b * NAC + i;
    float4 r = make_float4(0.f, 0.f, 0.f, 0.f);
    if ((posm >> t) & 1) {
      uint32_t o0, o1;
      threefry2x32(kp0, kp1, 0u, (uint32_t)f, &o0, &o1);
      const uint32_t bits = o0 ^ o1;
      union { uint32_t u; float flt; } cv;
      cv.u = (bits >> 9) | 0x3F800000u;
      if (cv.flt - 1.0f < th) {
        r = bbox2delta_calc(a[t], gbox[bidx[t]]);
      }
    }
    reinterpret_cast<float4*>(out + (size_t)f * 8)[1] = r;
  }
}

// ---------------- Fallback path (proven two-kernel, flag in out[4]) ----------
__global__ __launch_bounds__(BLK) void k1_classify(
    const float* __restrict__ anchors,
    const float* __restrict__ gt,
    const float* __restrict__ deltas,
    float* __restrict__ out,
    int* __restrict__ counts)
{
  __shared__ __align__(16) float4 gbox[NGT];
  __shared__ __align__(16) float  garea[NGT];
  __shared__ __align__(16) float  gae[NGT];
  __shared__ int s_cnt;
  const int b   = blockIdx.y;
  const int tid = threadIdx.x;

  if (tid == 0) s_cnt = 0;
  if (tid < NGT) {
    float4 g = reinterpret_cast<const float4*>(gt)[b * NGT + tid];
    const float ga = fmaxf(g.z - g.x, 0.0f) * fmaxf(g.w - g.y, 0.0f);
    gbox[tid]  = g;
    garea[tid] = ga;
    gae[tid]   = ga + 1e-5f;
  }
  __syncthreads();

  const int base = blockIdx.x * (BLK * APT) + tid;

  float4 a[APT];
  float  areaA[APT], num[APT], Tb[APT];
  int    bidx[APT];
#pragma unroll
  for (int t = 0; t < APT; ++t) {
    a[t] = reinterpret_cast<const float4*>(anchors)[base + t * BLK];
    areaA[t] = fmaxf(a[t].z - a[t].x, 0.0f) * fmaxf(a[t].w - a[t].y, 0.0f);
    num[t]  = 0.0f;
    Tb[t]   = 1.0f;
    bidx[t] = 0;
  }

  for (int jj = 0; jj < NGT; jj += 4) {
    const float4 te4 = *reinterpret_cast<const float4*>(&gae[jj]);
    const float4 g0 = gbox[jj + 0];
    const float4 g1 = gbox[jj + 1];
    const float4 g2 = gbox[jj + 2];
    const float4 g3 = gbox[jj + 3];
    const float4 gs[4] = { g0, g1, g2, g3 };
#pragma unroll
    for (int u = 0; u < 4; ++u) {
      const float4 g  = gs[u];
      const float  te = (&te4.x)[u];
      const int    j  = jj + u;
#pragma unroll
      for (int t = 0; t < APT; ++t) {
        float yi = fmaxf(a[t].x, g.x);
        float xi = fmaxf(a[t].y, g.y);
        float ya = fminf(a[t].z, g.z);
        float xa = fminf(a[t].w, g.w);
        float inter = fmaxf(ya - yi, 0.0f) * (xa - xi);
        float Tj = areaA[t] + te;
        bool upd = inter * Tb[t] > num[t] * Tj;
        num[t]  = upd ? inter : num[t];
        Tb[t]   = upd ? Tj    : Tb[t];
        bidx[t] = upd ? j     : bidx[t];
      }
    }
  }

  int npos = 0;
#pragma unroll
  for (int t = 0; t < APT; ++t) {
    const int i = base + t * BLK;
    const float gaB = garea[bidx[t]];
    const float den = ((areaA[t] + gaB) - num[t]) + 1e-5f;
    const float best_iou = (10000.0f * num[t]) / den;
    const bool pos = best_iou > 5000.0f;

    const float4 d = reinterpret_cast<const float4*>(deltas)[b * NAC + i];
    const float wb = a[t].w - a[t].y, hb = a[t].z - a[t].x;
    const float xc = a[t].y + 0.5f * wb + wb * d.x;
    const float yc = a[t].x + 0.5f * hb + hb * d.y;
    const float w_ = wb * __expf(d.z);
    const float h_ = hb * __expf(d.w);

    float* rowp = out + ((size_t)b * NAC + i) * 8;
    reinterpret_cast<float4*>(rowp)[0] =
        make_float4(yc - 0.5f * h_, xc - 0.5f * w_, yc + 0.5f * h_, xc + 0.5f * w_);
    reinterpret_cast<float4*>(rowp)[1] =
        make_float4(pos ? (float)(bidx[t] + 1) : 0.0f, 0.f, 0.f, 0.f);

    unsigned long long m = __ballot(pos);
    if ((tid & 63) == 0) npos += (int)__popcll(m);
  }
  if ((tid & 63) == 0 && npos)
    atomicAdd(&s_cnt, npos);
  __syncthreads();

  if (tid == 0 && s_cnt) atomicAdd(&counts[b], s_cnt);
}

__global__ __launch_bounds__(256) void k2_fallback(
    const float* __restrict__ anchors,
    const float* __restrict__ gt,
    float* __restrict__ out,
    const int* __restrict__ counts,
    uint32_t kp0, uint32_t kp1)
{
  const int b = blockIdx.y;
  const int i = blockIdx.x * 256 + threadIdx.x;
  const int f = b * NAC + i;
  float* rowp = out + (size_t)f * 8;

  const float flag = rowp[4];
  if (flag == 0.0f) return;

  const float th = 128.0f / ((float)counts[b] + 1e-6f);

  uint32_t o0, o1;
  threefry2x32(kp0, kp1, 0u, (uint32_t)f, &o0, &o1);
  const uint32_t bits = o0 ^ o1;
  union { uint32_t u; float flt; } cv;
  cv.u = (bits >> 9) | 0x3F800000u;

  if (cv.flt - 1.0f < th) {
    const float4 a = reinterpret_cast<const float4*>(anchors)[i];
    const float4 g = reinterpret_cast<const float4*>(gt)[b * NGT + ((int)flag - 1)];
    float4 r = bbox2delta_calc(a, g);
    *reinterpret_cast<float4*>(rowp + 4) = r;
  } else {
    reinterpret_cast<float4*>(rowp)[1] = make_float4(0.f, 0.f, 0.f, 0.f);
  }
}

extern "C" void kernel_launch(void* const* d_in, const int* in_sizes, int n_in,
                              void* d_out, int out_size, void* d_ws, size_t ws_size,
                              hipStream_t stream)
{
  const float* anchors = (const float*)d_in[0];
  const float* gt      = (const float*)d_in[1];
  const float* deltas  = (const float*)d_in[2];
  float* out  = (float*)d_out;
  int* cnt = (int*)d_ws;          // [NB]
  int* arr = (int*)d_ws + NB;     // [NB]

  // kp = jax.random.split(jax.random.key(42))[0], threefry_partitionable:
  // kp = threefry2x32((0,42), 0, 0), full pair. (Verified rounds 2/3/5-9.)
  uint32_t kp0, kp1;
  threefry2x32(0u, 42u, 0u, 0u, &kp0, &kp1);

  hipMemsetAsync(d_ws, 0, 2 * NB * sizeof(int), stream);

  if (ws_size >= 2 * NB * sizeof(int)) {
    dim3 g1(GX, NB);   // 1536 blocks = 6/CU, all co-resident (see launch_bounds)
    k_fused<<<g1, dim3(BLK), 0, stream>>>(anchors, gt, deltas, out,
                                          cnt, arr, kp0, kp1);
  } else {
    dim3 g1(GX, NB);
    k1_classify<<<g1, dim3(BLK), 0, stream>>>(anchors, gt, deltas, out, cnt);
    dim3 g2(NAC / 256, NB);
    k2_fallback<<<g2, dim3(256), 0, stream>>>(anchors, gt, out, cnt,
                                              kp0, kp1);
  }
}

// Round 8
// 115.067 us; speedup vs baseline: 2.8691x; 2.8691x over previous
//
#include <hip/hip_runtime.h>
#include <stdint.h>

#define NAC 147456   // 128*128*9
#define NGT 64
#define NB  8
#define APT 3        // anchors per thread in k1 — measured optimum (round 8)
#define BLK 256
#define GX  (NAC / (BLK * APT))   // 192 -> grid 192x8 = 1536 blocks = 6/CU exact
#define LCAP 36864   // per-image pos-list capacity (25% of NAC; real pos ~2-3%)

// ---------------- Threefry-2x32 (JAX-compatible, 20 rounds) ----------------
__host__ __device__ static inline uint32_t tf_rotl(uint32_t x, uint32_t d) {
  return (x << d) | (x >> (32u - d));
}

__host__ __device__ static inline void threefry2x32(
    uint32_t k0, uint32_t k1, uint32_t x0, uint32_t x1,
    uint32_t* o0, uint32_t* o1)
{
  const uint32_t ks2 = k0 ^ k1 ^ 0x1BD11BDAu;
  x0 += k0; x1 += k1;
#define TFR(r) { x0 += x1; x1 = tf_rotl(x1, (r)); x1 ^= x0; }
  TFR(13u) TFR(15u) TFR(26u) TFR(6u)   x0 += k1;  x1 += ks2 + 1u;
  TFR(17u) TFR(29u) TFR(16u) TFR(24u)  x0 += ks2; x1 += k0 + 2u;
  TFR(13u) TFR(15u) TFR(26u) TFR(6u)   x0 += k0;  x1 += k1 + 3u;
  TFR(17u) TFR(29u) TFR(16u) TFR(24u)  x0 += k1;  x1 += ks2 + 4u;
  TFR(13u) TFR(15u) TFR(26u) TFR(6u)   x0 += ks2; x1 += k0 + 5u;
#undef TFR
  *o0 = x0; *o1 = x1;
}

__device__ static inline void bbox2delta_store(
    const float4& a, const float4& g, float* dst)
{
  const float wr  = a.w - a.y,          hr  = a.z - a.x;
  const float xcr = a.y + 0.5f * wr,    ycr = a.x + 0.5f * hr;
  const float wrc = fmaxf(wr, 1e-5f),   hrc = fmaxf(hr, 1e-5f);
  const float wl  = g.w - g.y,          hl  = g.z - g.x;
  const float xcl = g.y + 0.5f * wl,    ycl = g.x + 0.5f * hl;
  float4 r;
  r.x = fminf(fmaxf((xcl - xcr) / wrc, -10.0f), 10.0f);
  r.y = fminf(fmaxf((ycl - ycr) / hrc, -10.0f), 10.0f);
  r.z = fminf(fmaxf(__logf(wl / wrc),  -10.0f), 10.0f);
  r.w = fminf(fmaxf(__logf(hl / hrc),  -10.0f), 10.0f);
  *reinterpret_cast<float4*>(dst) = r;
}

// ---------------- Kernel 1: IoU argmax + proposals + pos-list ---------------
// Round-17. Fusion is DEAD (r13: coop-launch path overhead; r16: spin-barrier
// caused RMW write-doubling + cross-XCD atomic meltdown, 255us). Back to the
// proven r12 two-kernel structure (116.2us), attacking the ~28us k2 slice:
// k1 now emits a COMPACT per-image list of pos anchors (i | bidx<<18) instead
// of a 1.2MB flags array. k2 reads cnt[b] + ~3.5K entries/image (~110KB) and
// only does threefry + delta for listed anchors. k1 write -1.2MB, k2 fetch
// -1.1MB, and k2's 192-way count reduction disappears.
// Inner loop = r12's proven form, pinned at ~43.5us across 4 structural
// variants (dense/SMEM/pipelined/APT1-full-occupancy) -> issue-bound floor.
// pos threshold BIT-IDENTICAL: epilogue recomputes den in reference rounding
// order ((areaA+ga)-inter)+EPS, ONE IEEE div per anchor.
// List order is irrelevant: sampling key is threefry(f), f = b*NAC+i, fixed
// per anchor regardless of list position.
// LCAP clamp: reserve-then-clamp keeps cnt[b] exact for the threshold even
// in the (impossible on this data: pos ~2-3% << 25%) overflow case.
template <bool USE_LIST>
__global__ __launch_bounds__(BLK) void k1_classify(
    const float* __restrict__ anchors,
    const float* __restrict__ gt,
    const float* __restrict__ deltas,
    float* __restrict__ out,
    int* __restrict__ cnt,              // [NB], pre-zeroed
    uint32_t* __restrict__ list)        // [NB*LCAP] (USE_LIST only)
{
  __shared__ __align__(16) float4 gbox[NGT];
  __shared__ __align__(16) float  garea[NGT];   // ga_j (exact, epilogue den)
  __shared__ __align__(16) float  gae[NGT];     // ga_j + EPS (T_j in compare)
  __shared__ int s_cnt;
  __shared__ int s_base;
  const int b   = blockIdx.y;
  const int tid = threadIdx.x;

  if (tid == 0) s_cnt = 0;
  if (tid < NGT) {
    float4 g = reinterpret_cast<const float4*>(gt)[b * NGT + tid];
    const float ga = fmaxf(g.z - g.x, 0.0f) * fmaxf(g.w - g.y, 0.0f);
    gbox[tid]  = g;
    garea[tid] = ga;
    gae[tid]   = ga + 1e-5f;
  }
  __syncthreads();

  const int base = blockIdx.x * (BLK * APT) + tid;

  float4 a[APT];
  float  areaA[APT], num[APT], Tb[APT];
  int    bidx[APT];
#pragma unroll
  for (int t = 0; t < APT; ++t) {
    a[t] = reinterpret_cast<const float4*>(anchors)[base + t * BLK];
    areaA[t] = fmaxf(a[t].z - a[t].x, 0.0f) * fmaxf(a[t].w - a[t].y, 0.0f);
    num[t]  = 0.0f;   // incumbent inter
    Tb[t]   = 1.0f;   // incumbent S+e; any >0 gives "update iff inter>0" init
    bidx[t] = 0;
  }

  for (int jj = 0; jj < NGT; jj += 4) {
    const float4 te4 = *reinterpret_cast<const float4*>(&gae[jj]);
    const float4 g0 = gbox[jj + 0];
    const float4 g1 = gbox[jj + 1];
    const float4 g2 = gbox[jj + 2];
    const float4 g3 = gbox[jj + 3];
    const float4 gs[4] = { g0, g1, g2, g3 };
#pragma unroll
    for (int u = 0; u < 4; ++u) {
      const float4 g  = gs[u];
      const float  te = (&te4.x)[u];
      const int    j  = jj + u;
#pragma unroll
      for (int t = 0; t < APT; ++t) {
        float yi = fmaxf(a[t].x, g.x);
        float xi = fmaxf(a[t].y, g.y);
        float ya = fminf(a[t].z, g.z);
        float xa = fminf(a[t].w, g.w);
        float inter = fmaxf(ya - yi, 0.0f) * (xa - xi);
        float Tj = areaA[t] + te;
        // iou_j > iou_best  <=>  inter*T_best > num*T_j  (both T > 0; exact:
        // update needs inter*Tb > num*Tj >= 0, impossible unless both gaps > 0)
        bool upd = inter * Tb[t] > num[t] * Tj;
        num[t]  = upd ? inter : num[t];
        Tb[t]   = upd ? Tj    : Tb[t];
        bidx[t] = upd ? j     : bidx[t];
      }
    }
  }

  int slot[APT];
#pragma unroll
  for (int t = 0; t < APT; ++t) {
    const int i = base + t * BLK;
    // Exact reference rounding order for the pos test:
    // den = ((areaA + ga_best) - inter_best) + EPS ; iou = (10000*inter)/den
    const float gaB = garea[bidx[t]];
    const float den = ((areaA[t] + gaB) - num[t]) + 1e-5f;
    const float best_iou = (10000.0f * num[t]) / den;
    const bool pos = best_iou > 5000.0f;
    slot[t] = pos ? atomicAdd(&s_cnt, 1) : -1;   // LDS atomic, ~25/block

    const float4 d = reinterpret_cast<const float4*>(deltas)[b * NAC + i];
    const float wb = a[t].w - a[t].y, hb = a[t].z - a[t].x;
    const float xc = a[t].y + 0.5f * wb + wb * d.x;
    const float yc = a[t].x + 0.5f * hb + hb * d.y;
    const float w_ = wb * __expf(d.z);
    const float h_ = hb * __expf(d.w);

    float* rowp = out + ((size_t)b * NAC + i) * 8;
    reinterpret_cast<float4*>(rowp)[0] =
        make_float4(yc - 0.5f * h_, xc - 0.5f * w_, yc + 0.5f * h_, xc + 0.5f * w_);
    if (USE_LIST) {
      reinterpret_cast<float4*>(rowp)[1] = make_float4(0.f, 0.f, 0.f, 0.f);
    } else {
      reinterpret_cast<float4*>(rowp)[1] =
          make_float4(pos ? (float)(bidx[t] + 1) : 0.0f, 0.f, 0.f, 0.f);
    }
  }
  __syncthreads();
  if (tid == 0) {
    s_base = s_cnt ? atomicAdd(&cnt[b], s_cnt) : 0;
  }
  __syncthreads();

  if (USE_LIST) {
#pragma unroll
    for (int t = 0; t < APT; ++t) {
      if (slot[t] >= 0) {
        const int e = s_base + slot[t];
        if (e < LCAP) {
          const int i = base + t * BLK;
          list[b * LCAP + e] = (uint32_t)i | ((uint32_t)bidx[t] << 18);
        }
      }
    }
  }
}

// ---------------- Kernel 2a (list): sparse sampling over compact list --------
__global__ __launch_bounds__(256) void k2_list(
    const float* __restrict__ anchors,
    const float* __restrict__ gt,
    float* __restrict__ out,
    const int* __restrict__ cnt,
    const uint32_t* __restrict__ list,
    uint32_t kp0, uint32_t kp1)
{
  const int b   = blockIdx.y;
  const int tid = threadIdx.x;

  int tot = cnt[b];
  const float th = 128.0f / ((float)tot + 1e-6f);
  if (tot > LCAP) tot = LCAP;

  for (int e = blockIdx.x * 256 + tid; e < tot; e += 16 * 256) {
    const uint32_t p = list[b * LCAP + e];
    const int i  = (int)(p & 0x3FFFFu);
    const int fl = (int)(p >> 18);          // bidx, 0..63
    const int f  = b * NAC + i;

    uint32_t o0, o1;
    threefry2x32(kp0, kp1, 0u, (uint32_t)f, &o0, &o1);
    const uint32_t bits = o0 ^ o1;
    union { uint32_t u; float flt; } cv;
    cv.u = (bits >> 9) | 0x3F800000u;
    if (cv.flt - 1.0f < th) {
      const float4 a = reinterpret_cast<const float4*>(anchors)[i];
      const float4 g = reinterpret_cast<const float4*>(gt)[b * NGT + fl];
      bbox2delta_store(a, g, out + (size_t)f * 8 + 4);
    }
  }
}

// ---------------- Kernel 2b (fallback, proven): flag in out[4] ---------------
__global__ __launch_bounds__(256) void k2_fallback(
    const float* __restrict__ anchors,
    const float* __restrict__ gt,
    float* __restrict__ out,
    const int* __restrict__ counts,
    uint32_t kp0, uint32_t kp1)
{
  const int b = blockIdx.y;
  const int i = blockIdx.x * 256 + threadIdx.x;
  const int f = b * NAC + i;
  float* rowp = out + (size_t)f * 8;

  const float flag = rowp[4];
  if (flag == 0.0f) return;

  const float th = 128.0f / ((float)counts[b] + 1e-6f);

  uint32_t o0, o1;
  threefry2x32(kp0, kp1, 0u, (uint32_t)f, &o0, &o1);
  const uint32_t bits = o0 ^ o1;
  union { uint32_t u; float flt; } cv;
  cv.u = (bits >> 9) | 0x3F800000u;

  if (cv.flt - 1.0f < th) {
    const float4 a = reinterpret_cast<const float4*>(anchors)[i];
    const float4 g = reinterpret_cast<const float4*>(gt)[b * NGT + ((int)flag - 1)];
    bbox2delta_store(a, g, rowp + 4);
  } else {
    reinterpret_cast<float4*>(rowp)[1] = make_float4(0.f, 0.f, 0.f, 0.f);
  }
}

extern "C" void kernel_launch(void* const* d_in, const int* in_sizes, int n_in,
                              void* d_out, int out_size, void* d_ws, size_t ws_size,
                              hipStream_t stream)
{
  const float* anchors = (const float*)d_in[0];
  const float* gt      = (const float*)d_in[1];
  const float* deltas  = (const float*)d_in[2];
  float* out  = (float*)d_out;
  int* cnt = (int*)d_ws;                                   // [NB] ints
  uint32_t* list = (uint32_t*)((char*)d_ws + 256);         // [NB*LCAP] u32

  const bool use_list = ws_size >= (size_t)(256 + NB * LCAP * 4);

  // kp = jax.random.split(jax.random.key(42))[0], threefry_partitionable:
  // kp = threefry2x32((0,42), 0, 0), full pair. (Verified rounds 2/3/5-9.)
  uint32_t kp0, kp1;
  threefry2x32(0u, 42u, 0u, 0u, &kp0, &kp1);

  hipMemsetAsync(cnt, 0, NB * sizeof(int), stream);

  dim3 g1(GX, NB);   // (192, 8) = 1536 blocks, 6/CU exact
  if (use_list) {
    k1_classify<true><<<g1, dim3(BLK), 0, stream>>>(anchors, gt, deltas, out,
                                                    cnt, list);
    dim3 g2(16, NB);   // compact list: ~3.5K entries/image
    k2_list<<<g2, dim3(256), 0, stream>>>(anchors, gt, out, cnt, list,
                                          kp0, kp1);
  } else {
    k1_classify<false><<<g1, dim3(BLK), 0, stream>>>(anchors, gt, deltas, out,
                                                     cnt, nullptr);
    dim3 g2(NAC / 256, NB);        // (576, 8)
    k2_fallback<<<g2, dim3(256), 0, stream>>>(anchors, gt, out, cnt,
                                              kp0, kp1);
  }
}